// Round 1
// baseline (146.516 us; speedup 1.0000x reference)
//
#include <hip/hip_runtime.h>
#include <stdint.h>

// ---------------------------------------------------------------------------
// PoseFeatureExtractor fused kernel for MI355X (gfx950) — round 5
//   - Temporal fold: vel/acc (and jw) folded into W1 -> phase 0c vanishes;
//     GEMM1 reads centered coords at 3 frame offsets (K=352).
//     Per-batch frame clamping reproduces reference zero-padding exactly.
//   - Poses staged once into LDS (coalesced), all phase-0 reads from LDS.
//   - fp16 MFMA path (same rate as bf16, 4 more mantissa bits) -> fold-safe.
//   - No integer div/mod in the hot kernel; LDS 44480 B -> 3 blocks/CU.
// ---------------------------------------------------------------------------

#define S_    2048
#define MT_   64
#define TPB   512
#define HID_  256
#define OUT_  128
#define NTOK  131072                 // 64 * 2048 tokens

typedef __attribute__((ext_vector_type(8))) _Float16 half8;   // fp16x8 MFMA frag
typedef __attribute__((ext_vector_type(4))) float    floatx4; // fp32x4 MFMA acc

// edge tables packed as nibbles: c0[e] = (C0M>>4e)&15 ; c1[e] = ((C1M>>4e)&15)+1
#define C0M 0x0ECDB118675110ULL
#define C1M 0x0FDECBA9786540ULL

// |err| <= 6.7e-5 abs (A&S 4.4.45) — far below fp16 feature quantization
__device__ __forceinline__ float facos(float x) {
    float ax = fabsf(x);
    float p = fmaf(ax, -0.0187293f, 0.0742610f);
    p = fmaf(ax, p, -0.2121144f);
    p = fmaf(ax, p, 1.5707288f);
    float r = __builtin_amdgcn_sqrtf(1.f - ax) * p;
    return x < 0.f ? 3.14159265358979f - r : r;
}

// --------------------------- prep kernel -----------------------------------
// Build W1'' (BN-fold + temporal-fold + jw-fold), fp16, MFMA-B-fragment order.
// K layout: [cc(s) 0..95][cc(s-1) 96..191][cc(s-2) 192..287][ang 288..351]
//   d0 rows: (Wp+Wv+Wa)*a*jw ; d1: -(Wv+2Wa)*a*jw ; d2: Wa*a*jw ; ang: Wang*a*jw
__global__ void prep_kernel(const float* __restrict__ W1, const float* __restrict__ b1,
                            const float* __restrict__ gamma, const float* __restrict__ beta,
                            const float* __restrict__ rmean, const float* __restrict__ rvar,
                            const float* __restrict__ W2, const float* __restrict__ jw,
                            _Float16* __restrict__ w1p,
                            _Float16* __restrict__ w2p,
                            float* __restrict__ b1p) {
    int idx = blockIdx.x * 256 + threadIdx.x;
    if (idx < 352 * 256) {                   // W1'' folded + packed (K=352)
        int k = idx >> 8, n = idx & 255;
        float a = gamma[n] * __builtin_amdgcn_rsqf(rvar[n] + 1e-5f);
        float v = 0.f;
        if (k < 288) {
            int d = k / 96, loc = k - d * 96;
            if (loc < 75) {
                int j = loc / 3, c = loc - j * 3;
                const float* Wb = W1 + (j * 12 + c) * HID_ + n;
                float wp = Wb[0], wv = Wb[3 * HID_], wa = Wb[6 * HID_];
                float t = (d == 0) ? (wp + wv + wa) : (d == 1 ? -(wv + 2.f * wa) : wa);
                v = t * a * jw[j];
            }
        } else {
            int q = k - 288;
            if (q < 39) {
                int e = q / 3, aa = q - e * 3;
                v = W1[(e * 12 + 9 + aa) * HID_ + n] * a * jw[e];
            }
        }
        int blk = (k >> 5) * 16 + (n >> 4);
        int off = blk * 512 + (((k >> 3) & 3) * 16 + (n & 15)) * 8 + (k & 7);
        w1p[off] = (_Float16)v;
    } else if (idx < 352 * 256 + 256 * 128) {    // W2 packed fp16
        int i2 = idx - 352 * 256;
        int k = i2 >> 7, n = i2 & 127;
        int blk = (k >> 5) * 8 + (n >> 4);
        int off = blk * 512 + (((k >> 3) & 3) * 16 + (n & 15)) * 8 + (k & 7);
        w2p[off] = (_Float16)W2[k * OUT_ + n];
    } else if (idx < 352 * 256 + 256 * 128 + 256) {  // folded bias
        int n = idx - (352 * 256 + 256 * 128);
        float a = gamma[n] * __builtin_amdgcn_rsqf(rvar[n] + 1e-5f);
        b1p[n] = fmaf(a, b1[n] - rmean[n], beta[n]);
    }
}

// --------------------------- main fused kernel ------------------------------
// LDS: ccb  66 x 104 halfs (stride 208 B, banks 20r mod 32 -> 2-way)  13728 B
//      ab   64 x 72  halfs (stride 144 B, banks  4r mod 32 -> 2-way)   9216 B
//      raw  5120 floats (staged poses, frames t0-2 .. t0+63 + pad)    20480 B
//      rs   66 float4 (root.xyz, scale)                                1056 B
//      hid (64 x 264 halfs = 33792 B) overlays ccb+ab+raw after GEMM1.
#define L_CCB 0
#define L_AB  13728
#define L_RAW 22944
#define L_RS  43424
#define L_TOT 44480                 // -> 3 blocks/CU, 24 waves

__global__ __launch_bounds__(TPB, 6) void pose_mlp(
    const float* __restrict__ poses,
    const _Float16* __restrict__ w1p,
    const _Float16* __restrict__ w2p,
    const float* __restrict__ b1p,
    const float* __restrict__ b2,
    float* __restrict__ out)
{
    __shared__ __align__(16) unsigned char smem[L_TOT];
    const int tid  = threadIdx.x;
    const int lane = tid & 63;
    const int wv   = tid >> 6;               // 0..7
    const int t0   = blockIdx.x * MT_;
    const int s0   = t0 & (S_ - 1);

    _Float16* ccb = (_Float16*)(smem + L_CCB);
    _Float16* ab  = (_Float16*)(smem + L_AB);
    float*    raw = (float*)(smem + L_RAW);
    float4*   rs  = (float4*)(smem + L_RS);

    // early prefetch: GEMM1 kc=0 B-frags (this wave's 2 n-tiles)
    half8 bw[2];
    #pragma unroll
    for (int ni = 0; ni < 2; ni++)
        bw[ni] = *(const half8*)(w1p + (unsigned)(wv * 2 + ni) * 512 + lane * 8);

    // ---- stage: poses frames (t0-2..t0+63) -> LDS, contiguous/coalesced ----
    // per-batch clamp: first block of a batch maps frames -2,-1 to frame 0.
    #pragma unroll
    for (int it = 0; it < 10; it++) {
        int i = it * TPB + tid;              // 0..5119 (4950 real + pad)
        int src = t0 * 75 - 150 + i;
        if (s0 == 0) { if (i < 75) src += 150; else if (i < 150) src += 75; }
        src = src < NTOK * 75 - 1 ? src : NTOK * 75 - 1;
        raw[i] = poses[src];
    }
    __syncthreads();

    // ---- 0b: root + scale per frame (66 frames, 2 lanes/frame) ----
    if (tid < 132) {
        int f = tid >> 1, h = tid & 1;
        const float* R = raw + f * 75;
        float r0 = R[0], r1 = R[1], r2 = R[2];
        float m2 = 0.f;
        #pragma unroll
        for (int jj = 0; jj < 13; jj++) {
            int j = h * 13 + jj;
            if (j < 25) {
                float dx = R[j * 3]     - r0;
                float dy = R[j * 3 + 1] - r1;
                float dz = R[j * 3 + 2] - r2;
                m2 = fmaxf(m2, fmaf(dx, dx, fmaf(dy, dy, dz * dz)));
            }
        }
        m2 = fmaxf(m2, __shfl_xor(m2, 1));
        if (h == 0) {
            float sc = __builtin_amdgcn_rcpf(__builtin_amdgcn_sqrtf(m2) + 1e-8f);
            rs[f] = make_float4(r0, r1, r2, sc);
        }
    }
    __syncthreads();

    // ---- 0c: center+scale -> ccb fp16 (j>=25 lanes zero the K-pad 75..95) ----
    #pragma unroll 1
    for (int i = tid; i < 66 * 32; i += TPB) {
        int f = i >> 5, j = i & 31;
        _Float16* C = ccb + f * 104;
        if (j < 25) {
            const float* R = raw + f * 75 + j * 3;
            float4 q = rs[f];
            C[j * 3 + 0] = (_Float16)((R[0] - q.x) * q.w);
            C[j * 3 + 1] = (_Float16)((R[1] - q.y) * q.w);
            C[j * 3 + 2] = (_Float16)((R[2] - q.z) * q.w);
        } else {
            int c = 75 + (j - 25) * 3;
            C[c] = (_Float16)0.f; C[c + 1] = (_Float16)0.f; C[c + 2] = (_Float16)0.f;
        }
    }

    // ---- 0d: joint angles -> ab fp16 (e>=13 lanes zero the K-pad 39..63) ----
    // v/||v|| invariant to centering + positive scale -> use raw coords.
    #pragma unroll 1
    for (int i = tid; i < 64 * 16; i += TPB) {
        int tt = i >> 4, e = i & 15;
        _Float16* A = ab + tt * 72;
        if (e < 13) {
            const float* R = raw + (tt + 2) * 75;
            int a0 = (int)((C0M >> (4 * e)) & 15) * 3;
            int a1 = (((int)((C1M >> (4 * e)) & 15)) + 1) * 3;
            float vx = R[a1] - R[a0], vy = R[a1 + 1] - R[a0 + 1], vz = R[a1 + 2] - R[a0 + 2];
            float d  = fmaf(vx, vx, fmaf(vy, vy, vz * vz));
            float inv = __builtin_amdgcn_rcpf(fmaxf(__builtin_amdgcn_sqrtf(d), 1e-12f));
            A[e * 3 + 0] = (_Float16)facos(fminf(fmaxf(vx * inv, -1.f), 1.f));
            A[e * 3 + 1] = (_Float16)facos(fminf(fmaxf(vy * inv, -1.f), 1.f));
            A[e * 3 + 2] = (_Float16)facos(fminf(fmaxf(vz * inv, -1.f), 1.f));
        } else {
            int c0 = 39 + (e - 13);
            #pragma unroll
            for (int k = 0; k < 9; k++) { int c = c0 + 3 * k; if (c < 64) A[c] = (_Float16)0.f; }
        }
    }
    __syncthreads();

    // ---- GEMM1: hid = relu(A @ W1'' + b1'); K=352 (3 shifted cc reads + ang)
    floatx4 acc[4][2];
    #pragma unroll
    for (int mi = 0; mi < 4; mi++)
        #pragma unroll
        for (int ni = 0; ni < 2; ni++) acc[mi][ni] = (floatx4){0.f, 0.f, 0.f, 0.f};

    unsigned rowb[4];
    #pragma unroll
    for (int mi = 0; mi < 4; mi++)           // (token+2)*104 + (l>>4)*8
        rowb[mi] = (unsigned)(mi * 16 + (lane & 15) + 2) * 104 + (lane >> 4) * 8;

    int ko = 0, fofs = 0;                    // region-local k, frame-shift offset
    #pragma unroll 1
    for (int kc = 0; kc < 9; kc++) {         // cc regions d = kc/3
        half8 bn[2];
        #pragma unroll
        for (int ni = 0; ni < 2; ni++)
            bn[ni] = *(const half8*)(w1p + (unsigned)((kc + 1) * 16 + wv * 2 + ni) * 512 + lane * 8);
        half8 af[4];
        #pragma unroll
        for (int mi = 0; mi < 4; mi++)
            af[mi] = *(const half8*)(ccb + rowb[mi] + ko - fofs);
        #pragma unroll
        for (int mi = 0; mi < 4; mi++)
            #pragma unroll
            for (int ni = 0; ni < 2; ni++)
                acc[mi][ni] = __builtin_amdgcn_mfma_f32_16x16x32_f16(
                    af[mi], bw[ni], acc[mi][ni], 0, 0, 0);
        bw[0] = bn[0]; bw[1] = bn[1];
        ko += 32; if (ko == 96) { ko = 0; fofs += 104; }
    }
    {   // kc = 9,10: angle region from ab
        unsigned rowa[4];
        #pragma unroll
        for (int mi = 0; mi < 4; mi++)
            rowa[mi] = (unsigned)(mi * 16 + (lane & 15)) * 72 + (lane >> 4) * 8;
        #pragma unroll
        for (int kc = 9; kc < 11; kc++) {
            half8 bn[2];
            if (kc < 10) {
                #pragma unroll
                for (int ni = 0; ni < 2; ni++)
                    bn[ni] = *(const half8*)(w1p + (unsigned)((kc + 1) * 16 + wv * 2 + ni) * 512 + lane * 8);
            }
            half8 af[4];
            #pragma unroll
            for (int mi = 0; mi < 4; mi++)
                af[mi] = *(const half8*)(ab + rowa[mi] + (kc - 9) * 32);
            #pragma unroll
            for (int mi = 0; mi < 4; mi++)
                #pragma unroll
                for (int ni = 0; ni < 2; ni++)
                    acc[mi][ni] = __builtin_amdgcn_mfma_f32_16x16x32_f16(
                        af[mi], bw[ni], acc[mi][ni], 0, 0, 0);
            if (kc < 10) { bw[0] = bn[0]; bw[1] = bn[1]; }
        }
    }

    // preload W2 kc=0 frag (this wave's n-tile), independent of LDS
    half8 bw2 = *(const half8*)(w2p + (unsigned)wv * 512 + lane * 8);

    __syncthreads();   // all waves done reading ccb/ab

    _Float16* hid = (_Float16*)smem;         // 64 x 264, overlays ccb/ab/raw
    float bv[2];
    #pragma unroll
    for (int ni = 0; ni < 2; ni++) bv[ni] = b1p[wv * 32 + ni * 16 + (lane & 15)];
    #pragma unroll
    for (int mi = 0; mi < 4; mi++)
        #pragma unroll
        for (int ni = 0; ni < 2; ni++)
            #pragma unroll
            for (int r = 0; r < 4; r++) {
                float v = fmaxf(acc[mi][ni][r] + bv[ni], 0.f);
                int m   = mi * 16 + (lane >> 4) * 4 + r;   // C/D: row=(l>>4)*4+r
                int col = wv * 32 + ni * 16 + (lane & 15); //      col=l&15
                hid[m * 264 + col] = (_Float16)v;
            }
    __syncthreads();   // hid visible

    // ---- GEMM2: out = hid @ W2 + b2; wave wv owns n-tile wv ----
    floatx4 acc2[4];
    #pragma unroll
    for (int mi = 0; mi < 4; mi++) acc2[mi] = (floatx4){0.f, 0.f, 0.f, 0.f};

    #pragma unroll 1
    for (int kc = 0; kc < 8; kc++) {
        half8 bn2;
        if (kc < 7)
            bn2 = *(const half8*)(w2p + (unsigned)((kc + 1) * 8 + wv) * 512 + lane * 8);
        half8 af[4];
        #pragma unroll
        for (int mi = 0; mi < 4; mi++)
            af[mi] = *(const half8*)(hid + (mi * 16 + (lane & 15)) * 264 + kc * 32 + (lane >> 4) * 8);
        #pragma unroll
        for (int mi = 0; mi < 4; mi++)
            acc2[mi] = __builtin_amdgcn_mfma_f32_16x16x32_f16(
                af[mi], bw2, acc2[mi], 0, 0, 0);
        if (kc < 7) bw2 = bn2;
    }

    float c2 = b2[wv * 16 + (lane & 15)];
    #pragma unroll
    for (int mi = 0; mi < 4; mi++)
        #pragma unroll
        for (int r = 0; r < 4; r++) {
            int m   = mi * 16 + (lane >> 4) * 4 + r;
            int col = wv * 16 + (lane & 15);
            out[(size_t)(t0 + m) * OUT_ + col] = acc2[mi][r] + c2;
        }
}

// --------------------------- launch -----------------------------------------
extern "C" void kernel_launch(void* const* d_in, const int* in_sizes, int n_in,
                              void* d_out, int out_size, void* d_ws, size_t ws_size,
                              hipStream_t stream) {
    (void)in_sizes; (void)n_in; (void)out_size; (void)ws_size;
    const float* poses = (const float*)d_in[0];
    const float* W1    = (const float*)d_in[1];
    const float* b1    = (const float*)d_in[2];
    const float* gamma = (const float*)d_in[3];
    const float* beta  = (const float*)d_in[4];
    const float* rmean = (const float*)d_in[5];
    const float* rvar  = (const float*)d_in[6];
    const float* W2    = (const float*)d_in[7];
    const float* b2    = (const float*)d_in[8];
    const float* jw    = (const float*)d_in[9];

    _Float16* w1p = (_Float16*)d_ws;                         // 352*256 fp16
    _Float16* w2p = w1p + 352 * HID_;                        // 256*128 fp16
    float* b1p = (float*)((char*)d_ws + (352 * HID_ + HID_ * OUT_) * 2);

    prep_kernel<<<481, 256, 0, stream>>>(W1, b1, gamma, beta, rmean, rvar, W2, jw,
                                         w1p, w2p, b1p);
    pose_mlp<<<2048, TPB, 0, stream>>>(poses, w1p, w2p, b1p, b2, (float*)d_out);
}